// Round 2
// baseline (7398.960 us; speedup 1.0000x reference)
//
#include <hip/hip_runtime.h>
#include <hip/hip_bf16.h>

#define FDIM 15
#define HDIM 128
#define LNUM 12
#define NBINS 16
#define MDIM 47          // 3*NBINS-1
#define FM 705           // FDIM*MDIM
#define BATCH 65536
#define TAILF 3.0f
#define MIN_Wc 0.001f
#define MIN_Hc 0.001f
#define MIN_Dc 0.001f
#define SPB 16           // samples per block

// workspace layout (in floats)
#define NI (LNUM*FDIM*HDIM)        // 23040
#define NR (LNUM*4*HDIM*HDIM)      // 786432
#define NO (LNUM*HDIM*FM)          // 1082880
#define OFF_WI 0
#define OFF_WR (OFF_WI + NI)
#define OFF_WO (OFF_WR + NR)
#define OFF_X  (OFF_WO + NO)                 // BATCH*FDIM floats
#define OFF_LD (OFF_X + BATCH*FDIM)          // BATCH floats
#define WS_FLOATS (OFF_LD + BATCH)

__device__ __forceinline__ float sp_softplus(float u) {
    return (u > 20.f) ? u : log1pf(expf(u));
}

// Build masked, transposed fp32 weights from fp32 inputs.
__global__ void preproc_kernel(const float* __restrict__ Wi,
                               const float* __restrict__ Wr,
                               const float* __restrict__ Wo,
                               float* __restrict__ ws) {
    int idx = blockIdx.x * blockDim.x + threadIdx.x;
    const int total = NI + NR + NO;
    if (idx >= total) return;
    if (idx < NI) {
        // WtI[l][i][j] = W_init[l][j][i] * (deg_h[j] >= i+1)
        int j = idx % HDIM; int r = idx / HDIM; int i = r % FDIM; int l = r / FDIM;
        int degh = j % (FDIM - 1) + 1;
        float m = (degh >= i + 1) ? 1.f : 0.f;
        ws[OFF_WI + idx] = m * Wi[(l * HDIM + j) * FDIM + i];
    } else if (idx < NI + NR) {
        int id = idx - NI;
        // WtR[rr][k][j] = W_res[rr][j][k] * (deg_h[j] >= deg_h[k]), rr = l*4+blk*2+sub
        int j = id % HDIM; int r = id / HDIM; int k = r % HDIM; int rr = r / HDIM;
        int degj = j % 14 + 1, degk = k % 14 + 1;
        float m = (degj >= degk) ? 1.f : 0.f;
        ws[OFF_WR + id] = m * Wr[rr * HDIM * HDIM + j * HDIM + k];
    } else {
        int id = idx - NI - NR;
        // WtO[l][k][o] = W_out[l][o][k] * ((o/47+1) > deg_h[k])
        int o = id % FM; int r = id / FM; int k = r % HDIM; int l = r / HDIM;
        int dego = o / MDIM + 1; int degk = k % 14 + 1;
        float m = (dego > degk) ? 1.f : 0.f;
        ws[OFF_WO + id] = m * Wo[(l * FM + o) * HDIM + k];
    }
}

// 128->128 matmul with relu on input, thread owns column j, 8 samples.
__device__ __forceinline__ void mm128_relu(const float* __restrict__ W,
                                           const float (*src)[HDIM],
                                           int sh, int j, float bias, float* out8) {
    float acc[8];
#pragma unroll
    for (int q = 0; q < 8; q++) acc[q] = bias;
    for (int k4 = 0; k4 < 32; k4++) {
        float w0 = W[(k4 * 4 + 0) * HDIM + j];
        float w1 = W[(k4 * 4 + 1) * HDIM + j];
        float w2 = W[(k4 * 4 + 2) * HDIM + j];
        float w3 = W[(k4 * 4 + 3) * HDIM + j];
#pragma unroll
        for (int q = 0; q < 8; q++) {
            const float4 hv = *(const float4*)&src[sh * 8 + q][k4 * 4];
            acc[q] = fmaf(fmaxf(hv.x, 0.f), w0, acc[q]);
            acc[q] = fmaf(fmaxf(hv.y, 0.f), w1, acc[q]);
            acc[q] = fmaf(fmaxf(hv.z, 0.f), w2, acc[q]);
            acc[q] = fmaf(fmaxf(hv.w, 0.f), w3, acc[q]);
        }
    }
#pragma unroll
    for (int q = 0; q < 8; q++) out8[q] = acc[q];
}

__global__ __launch_bounds__(256) void layer_kernel(
    const float* __restrict__ x0,
    float* __restrict__ xbuf, float* __restrict__ ldbuf,
    const float* __restrict__ WtI, const float* __restrict__ bI,
    const float* __restrict__ WtR, const float* __restrict__ bR,
    const float* __restrict__ WtO, const float* __restrict__ bO,
    int layer) {
    __shared__ float xs[SPB][16];
    __shared__ float h[SPB][HDIM];
    __shared__ float t[SPB][HDIM];
    __shared__ float raw[SPB][720];
    __shared__ float ladv[SPB * FDIM];

    const int tid = threadIdx.x;
    const int s0 = blockIdx.x * SPB;

    // load & reverse x
    if (tid < SPB * FDIM) {
        int s = tid / FDIM, i = tid % FDIM;
        float v = (layer == 0) ? x0[(s0 + s) * FDIM + (FDIM - 1 - i)]
                               : xbuf[(s0 + s) * FDIM + (FDIM - 1 - i)];
        xs[s][i] = v;
    }
    __syncthreads();

    const int j = tid & 127, sh = tid >> 7;

    // h = xx @ WtI + b
    {
        float acc[8];
        float bias = bI[layer * HDIM + j];
#pragma unroll
        for (int q = 0; q < 8; q++) acc[q] = bias;
        const float* Wl = WtI + layer * FDIM * HDIM;
        for (int i = 0; i < FDIM; i++) {
            float w = Wl[i * HDIM + j];
#pragma unroll
            for (int q = 0; q < 8; q++) acc[q] = fmaf(xs[sh * 8 + q][i], w, acc[q]);
        }
#pragma unroll
        for (int q = 0; q < 8; q++) h[sh * 8 + q][j] = acc[q];
    }
    __syncthreads();

    // two residual blocks
    for (int blk = 0; blk < 2; blk++) {
        float t8[8];
        float b0 = bR[(layer * 4 + blk * 2 + 0) * HDIM + j];
        mm128_relu(WtR + (size_t)(layer * 4 + blk * 2 + 0) * HDIM * HDIM, h, sh, j, b0, t8);
#pragma unroll
        for (int q = 0; q < 8; q++) t[sh * 8 + q][j] = t8[q];
        __syncthreads();
        float b1 = bR[(layer * 4 + blk * 2 + 1) * HDIM + j];
        mm128_relu(WtR + (size_t)(layer * 4 + blk * 2 + 1) * HDIM * HDIM, t, sh, j, b1, t8);
#pragma unroll
        for (int q = 0; q < 8; q++) h[sh * 8 + q][j] += t8[q];
        __syncthreads();
    }

    // raw = h @ WtO + b  (no relu)
    {
        const float* W = WtO + (size_t)layer * HDIM * FM;
        for (int p = 0; p < 3; p++) {
            int o = tid + p * 256;
            if (o < FM) {
                float acc[16];
                float bias = bO[layer * FM + o];
#pragma unroll
                for (int s2 = 0; s2 < 16; s2++) acc[s2] = bias;
                for (int k4 = 0; k4 < 32; k4++) {
                    float w0 = W[(k4 * 4 + 0) * FM + o];
                    float w1 = W[(k4 * 4 + 1) * FM + o];
                    float w2 = W[(k4 * 4 + 2) * FM + o];
                    float w3 = W[(k4 * 4 + 3) * FM + o];
#pragma unroll
                    for (int s2 = 0; s2 < 16; s2++) {
                        const float4 hv = *(const float4*)&h[s2][k4 * 4];
                        acc[s2] = fmaf(hv.x, w0, acc[s2]);
                        acc[s2] = fmaf(hv.y, w1, acc[s2]);
                        acc[s2] = fmaf(hv.z, w2, acc[s2]);
                        acc[s2] = fmaf(hv.w, w3, acc[s2]);
                    }
                }
#pragma unroll
                for (int s2 = 0; s2 < 16; s2++) raw[s2][o] = acc[s2];
            }
        }
    }
    __syncthreads();

    // spline per (sample, feature)
    if (tid < SPB * FDIM) {
        int s = tid / FDIM, f = tid % FDIM;
        float xr = xs[s][f];
        bool inside = (xr >= -TAILF) && (xr <= TAILF);
        float xc = fminf(fmaxf(xr, -TAILF), TAILF);
        const float* rp = &raw[s][f * MDIM];

        float uw[NBINS], uh[NBINS];
        float mw = -1e30f, mh = -1e30f;
#pragma unroll
        for (int i = 0; i < NBINS; i++) {
            uw[i] = rp[i]; uh[i] = rp[NBINS + i];
            mw = fmaxf(mw, uw[i]); mh = fmaxf(mh, uh[i]);
        }
        float swv = 0.f, shv = 0.f;
#pragma unroll
        for (int i = 0; i < NBINS; i++) {
            uw[i] = expf(uw[i] - mw); swv += uw[i];
            uh[i] = expf(uh[i] - mh); shv += uh[i];
        }
        float isw = (1.f - NBINS * MIN_Wc) / swv;
        float ish = (1.f - NBINS * MIN_Hc) / shv;

        float cumw = 0.f, cumh = 0.f;
        float left = -TAILF, chl_run = -TAILF;
        float lw = -TAILF, wsel = 1.f, chl = -TAILF, hsel = 1.f;
        int idx = 0;
#pragma unroll
        for (int b = 0; b < NBINS; b++) {
            float wb = MIN_Wc + uw[b] * isw;
            float hb = MIN_Hc + uh[b] * ish;
            cumw += wb; cumh += hb;
            float cwr = (b == NBINS - 1) ? TAILF : 2.f * TAILF * cumw - TAILF;
            float chr = (b == NBINS - 1) ? TAILF : 2.f * TAILF * cumh - TAILF;
            bool inb = (xc >= left) && ((xc < cwr) || (b == NBINS - 1));
            if (inb) { idx = b; lw = left; wsel = cwr - left; chl = chl_run; hsel = chr - chl_run; }
            left = cwr; chl_run = chr;
        }
        float d0 = 1.f, d1 = 1.f;
        if (idx > 0)  d0 = MIN_Dc + sp_softplus(rp[2 * NBINS + idx - 1]);
        if (idx < NBINS - 1) d1 = MIN_Dc + sp_softplus(rp[2 * NBINS + idx]);

        float delta = hsel / wsel;
        float th = (xc - lw) / wsel;
        float omt = 1.f - th;
        float tomt = th * omt;
        float num = hsel * (delta * th * th + d0 * tomt);
        float den = delta + (d0 + d1 - 2.f * delta) * tomt;
        float y = chl + num / den;
        float dnum = delta * delta * (d1 * th * th + 2.f * delta * tomt + d0 * omt * omt);
        float lad = logf(dnum) - 2.f * logf(den);

        y = inside ? y : xr;
        lad = inside ? lad : 0.f;
        xbuf[(s0 + s) * FDIM + f] = y;
        ladv[tid] = lad;
    }
    __syncthreads();
    if (tid < SPB) {
        float sum = 0.f;
#pragma unroll
        for (int f = 0; f < FDIM; f++) sum += ladv[tid * FDIM + f];
        int gs = s0 + tid;
        ldbuf[gs] = (layer == 0) ? sum : ldbuf[gs] + sum;
    }
}

__global__ void epilogue_kernel(const float* __restrict__ xbuf,
                                const float* __restrict__ ldbuf,
                                float* __restrict__ out) {
    int i = blockIdx.x * blockDim.x + threadIdx.x;
    if (i < BATCH * FDIM) out[i] = xbuf[i];
    else if (i < BATCH * (FDIM + 1)) out[i] = ldbuf[i - BATCH * FDIM];
}

extern "C" void kernel_launch(void* const* d_in, const int* in_sizes, int n_in,
                              void* d_out, int out_size, void* d_ws, size_t ws_size,
                              hipStream_t stream) {
    const float* x  = (const float*)d_in[0];
    const float* Wi = (const float*)d_in[1];
    const float* bI = (const float*)d_in[2];
    const float* Wr = (const float*)d_in[3];
    const float* bR = (const float*)d_in[4];
    const float* Wo = (const float*)d_in[5];
    const float* bO = (const float*)d_in[6];
    float* ws = (float*)d_ws;

    const int totalW = NI + NR + NO;
    preproc_kernel<<<(totalW + 255) / 256, 256, 0, stream>>>(Wi, Wr, Wo, ws);

    for (int l = 0; l < LNUM; l++) {
        layer_kernel<<<BATCH / SPB, 256, 0, stream>>>(
            x, ws + OFF_X, ws + OFF_LD,
            ws + OFF_WI, bI, ws + OFF_WR, bR, ws + OFF_WO, bO, l);
    }

    epilogue_kernel<<<(BATCH * (FDIM + 1) + 255) / 256, 256, 0, stream>>>(
        ws + OFF_X, ws + OFF_LD, (float*)d_out);
}

// Round 3
// 1654.432 us; speedup vs baseline: 4.4722x; 4.4722x over previous
//
#include <hip/hip_runtime.h>
#include <hip/hip_bf16.h>

#define FDIM 15
#define HDIM 128
#define LNUM 12
#define NBINS 16
#define MDIM 47
#define FM 705
#define BATCH 65536
#define TAILF 3.0f
#define MIN_Wc 0.001f
#define MIN_Hc 0.001f
#define MIN_Dc 0.001f

typedef __bf16 bf16_t;
typedef __attribute__((ext_vector_type(8))) __bf16 bf16x8;
typedef __attribute__((ext_vector_type(4))) float f32x4;

// fragment counts per layer: init 8, residual 4*32=128, out 45*4=180 -> 316
#define FRAGS_PER_LAYER 316
#define FRAG_ELEMS 512          // 64 lanes * 8 bf16
#define WFRAG_TOTAL (LNUM * FRAGS_PER_LAYER * FRAG_ELEMS)

__device__ __forceinline__ float sp_softplus(float u) {
    return (u > 20.f) ? u : log1pf(expf(u));
}

// ---------------- preproc: build bf16 B-fragment-swizzled masked weights ----------------
// frag (l,g) at (l*316+g)*512 + lane*8 + j ; element = B[k = (lane>>4)*8 + j][n = tile*16 + (lane&15)]
__global__ void preproc_kernel(const float* __restrict__ Wi,
                               const float* __restrict__ Wr,
                               const float* __restrict__ Wo,
                               bf16_t* __restrict__ wfrag) {
    int idx = blockIdx.x * blockDim.x + threadIdx.x;
    if (idx >= WFRAG_TOTAL) return;
    int j = idx & 7;
    int lane = (idx >> 3) & 63;
    int fg = idx >> 9;
    int g = fg % FRAGS_PER_LAYER;
    int l = fg / FRAGS_PER_LAYER;
    int quad = lane >> 4, n16 = lane & 15;
    int kk = quad * 8 + j;      // k within 32-wide k-step
    float val = 0.f;
    if (g < 8) {
        // init: B[i][n] = W_init[l][n][i] * (deg_h[n] >= i+1), K padded 15->32
        int n = g * 16 + n16;
        if (kk < FDIM && (n % 14) >= kk)
            val = Wi[(l * HDIM + n) * FDIM + kk];
    } else if (g < 136) {
        int gg = g - 8;
        int mat = gg >> 5, rem = gg & 31, nt = rem >> 2, s = rem & 3;
        int k = s * 32 + kk;
        int jc = nt * 16 + n16;
        if ((jc % 14) >= (k % 14))
            val = Wr[((size_t)(l * 4 + mat) * HDIM + jc) * HDIM + k];
    } else {
        int gg = g - 136;
        int tt = gg >> 2, s = gg & 3;
        int k = s * 32 + kk;
        int f = tt / 3, ty = tt % 3;
        int o = (ty < 2) ? (f * MDIM + ty * 16 + n16)
                         : ((n16 < 15) ? (f * MDIM + 32 + n16) : -1);
        if (o >= 0 && (f + 1) > (k % 14 + 1))
            val = Wo[((size_t)l * FM + o) * HDIM + k];
    }
    wfrag[idx] = (bf16_t)val;
}

// ---------------- helpers ----------------
__device__ __forceinline__ void stage16x128(bf16_t (*A)[136], const f32x4* frags,
                                            int quad, int n16, bool relu) {
#pragma unroll
    for (int nt = 0; nt < 8; nt++) {
#pragma unroll
        for (int reg = 0; reg < 4; reg++) {
            float v = frags[nt][reg];
            if (relu) v = fmaxf(v, 0.f);
            A[quad * 4 + reg][nt * 16 + n16] = (bf16_t)v;
        }
    }
}

__device__ __forceinline__ void loadA(bf16x8* af, const bf16_t (*A)[136], int quad, int n16) {
#pragma unroll
    for (int s = 0; s < 4; s++)
        af[s] = *(const bf16x8*)&A[n16][s * 32 + quad * 8];
}

__device__ __forceinline__ void mm128(f32x4* dst, const bf16x8* af,
                                      const bf16_t* __restrict__ wb,
                                      const float* __restrict__ bias,
                                      int n16, int ln) {
#pragma unroll
    for (int nt = 0; nt < 8; nt++) {
        float bv = bias[nt * 16 + n16];
        f32x4 acc = {bv, bv, bv, bv};
#pragma unroll
        for (int s = 0; s < 4; s++) {
            bf16x8 b = *(const bf16x8*)(wb + ((nt * 4 + s) << 9) + ln * 8);
            acc = __builtin_amdgcn_mfma_f32_16x16x32_bf16(af[s], b, acc, 0, 0, 0);
        }
        dst[nt] = acc;
    }
}

// ---------------- main fused flow kernel: one wave = 16 samples, all 12 layers ----------------
__global__ __launch_bounds__(256, 2) void flow_kernel(
    const float* __restrict__ x0,
    const bf16_t* __restrict__ wfrag,
    const float* __restrict__ bI,
    const float* __restrict__ bR,
    const float* __restrict__ bO,
    float* __restrict__ out) {

    __shared__ __align__(16) bf16_t Ast[4][16][136];   // per-wave A staging (K=128, pad 8)
    __shared__ float raws[4][16][4][49];               // per-wave spline param transpose
    __shared__ float xss[4][16][17];                   // per-wave x carry

    const int wv = threadIdx.x >> 6, ln = threadIdx.x & 63;
    const int quad = ln >> 4, n16 = ln & 15;
    const int fi = ln & 3, srow = ln >> 2;
    const int sbase = (blockIdx.x * 4 + wv) * 16;

    bf16_t (*A)[136] = Ast[wv];
    float (*raw)[4][49] = raws[wv];
    float (*xs)[17] = xss[wv];

    // load x (16 samples x 15)
    for (int t = ln; t < 16 * FDIM; t += 64) {
        int s = t / FDIM, i = t % FDIM;
        xs[s][i] = x0[(size_t)(sbase + s) * FDIM + i];
    }

    float lad_acc = 0.f;

    for (int l = 0; l < LNUM; l++) {
        const bf16_t* wl = wfrag + (size_t)l * FRAGS_PER_LAYER * FRAG_ELEMS;

        // preload this lane's spline x-inputs (reversed frame) before xs gets overwritten
        float xc_pre[4];
#pragma unroll
        for (int c = 0; c < 4; c++) {
            int f = c * 4 + fi;
            xc_pre[c] = xs[srow][(f < FDIM) ? (14 - f) : 0];
        }

        // ---- init GEMM: A built in-register from reversed xs, K=32 (padded)
        bf16x8 a0;
#pragma unroll
        for (int j = 0; j < 8; j++) {
            int k = quad * 8 + j;
            float v = (k < FDIM) ? xs[n16][14 - k] : 0.f;
            a0[j] = (bf16_t)v;
        }
        f32x4 h[8];
#pragma unroll
        for (int nt = 0; nt < 8; nt++) {
            float bv = bI[l * HDIM + nt * 16 + n16];
            f32x4 acc = {bv, bv, bv, bv};
            bf16x8 b = *(const bf16x8*)(wl + ((size_t)nt << 9) + ln * 8);
            h[nt] = __builtin_amdgcn_mfma_f32_16x16x32_bf16(a0, b, acc, 0, 0, 0);
        }

        // ---- two residual blocks
        bf16x8 af[4];
#pragma unroll
        for (int blk = 0; blk < 2; blk++) {
            f32x4 t[8];
            stage16x128(A, h, quad, n16, true);
            loadA(af, A, quad, n16);
            mm128(t, af, wl + (size_t)(8 + (blk * 2 + 0) * 32) * FRAG_ELEMS,
                  bR + (size_t)(l * 4 + blk * 2 + 0) * HDIM, n16, ln);
            stage16x128(A, t, quad, n16, true);
            loadA(af, A, quad, n16);
            mm128(t, af, wl + (size_t)(8 + (blk * 2 + 1) * 32) * FRAG_ELEMS,
                  bR + (size_t)(l * 4 + blk * 2 + 1) * HDIM, n16, ln);
#pragma unroll
            for (int nt = 0; nt < 8; nt++) h[nt] += t[nt];
        }

        // ---- out GEMM staged A = h (no relu), reused across all chunks
        stage16x128(A, h, quad, n16, false);
        loadA(af, A, quad, n16);
        const bf16_t* wo = wl + (size_t)136 * FRAG_ELEMS;

#pragma unroll
        for (int c = 0; c < 4; c++) {
            const int nf = (c < 3) ? 4 : 3;
#pragma unroll
            for (int ff = 0; ff < 4; ff++) {
                if (ff >= nf) break;
                int f = c * 4 + ff;
#pragma unroll
                for (int ty = 0; ty < 3; ty++) {
                    int tt = f * 3 + ty;
                    int o = (ty < 2) ? (f * MDIM + ty * 16 + n16)
                                     : ((n16 < 15) ? (f * MDIM + 32 + n16) : -1);
                    float bv = (o >= 0) ? bO[(size_t)l * FM + o] : 0.f;
                    f32x4 acc = {bv, bv, bv, bv};
#pragma unroll
                    for (int s = 0; s < 4; s++) {
                        bf16x8 b = *(const bf16x8*)(wo + (((size_t)tt * 4 + s) << 9) + ln * 8);
                        acc = __builtin_amdgcn_mfma_f32_16x16x32_bf16(af[s], b, acc, 0, 0, 0);
                    }
#pragma unroll
                    for (int reg = 0; reg < 4; reg++)
                        raw[quad * 4 + reg][ff][ty * 16 + n16] = acc[reg];
                }
            }

            // ---- spline: one per lane (sample srow, feature c*4+fi)
            if (fi < nf) {
                int f = c * 4 + fi;
                const float* rp = raw[srow][fi];
                float xr = xc_pre[c];
                bool inside = (xr >= -TAILF) && (xr <= TAILF);
                float xcv = fminf(fmaxf(xr, -TAILF), TAILF);

                float uw[NBINS], uh[NBINS];
                float mw = -1e30f, mh = -1e30f;
#pragma unroll
                for (int i = 0; i < NBINS; i++) {
                    uw[i] = rp[i]; uh[i] = rp[NBINS + i];
                    mw = fmaxf(mw, uw[i]); mh = fmaxf(mh, uh[i]);
                }
                float swv = 0.f, shv = 0.f;
#pragma unroll
                for (int i = 0; i < NBINS; i++) {
                    uw[i] = expf(uw[i] - mw); swv += uw[i];
                    uh[i] = expf(uh[i] - mh); shv += uh[i];
                }
                float isw = (1.f - NBINS * MIN_Wc) / swv;
                float ish = (1.f - NBINS * MIN_Hc) / shv;

                float cumw = 0.f, cumh = 0.f;
                float left = -TAILF, chl_run = -TAILF;
                float lw = -TAILF, wsel = 1.f, chl = -TAILF, hsel = 1.f;
                int idx = 0;
#pragma unroll
                for (int b = 0; b < NBINS; b++) {
                    float wb = MIN_Wc + uw[b] * isw;
                    float hb = MIN_Hc + uh[b] * ish;
                    cumw += wb; cumh += hb;
                    float cwr = (b == NBINS - 1) ? TAILF : 2.f * TAILF * cumw - TAILF;
                    float chr = (b == NBINS - 1) ? TAILF : 2.f * TAILF * cumh - TAILF;
                    bool inb = (xcv >= left) && ((xcv < cwr) || (b == NBINS - 1));
                    if (inb) { idx = b; lw = left; wsel = cwr - left; chl = chl_run; hsel = chr - chl_run; }
                    left = cwr; chl_run = chr;
                }
                float d0 = 1.f, d1 = 1.f;
                if (idx > 0) d0 = MIN_Dc + sp_softplus(rp[2 * NBINS + idx - 1]);
                if (idx < NBINS - 1) d1 = MIN_Dc + sp_softplus(rp[2 * NBINS + idx]);

                float delta = hsel / wsel;
                float th = (xcv - lw) / wsel;
                float omt = 1.f - th;
                float tomt = th * omt;
                float num = hsel * (delta * th * th + d0 * tomt);
                float den = delta + (d0 + d1 - 2.f * delta) * tomt;
                float y = chl + num / den;
                float dnum = delta * delta * (d1 * th * th + 2.f * delta * tomt + d0 * omt * omt);
                float lad = logf(dnum) - 2.f * logf(den);

                y = inside ? y : xr;
                lad = inside ? lad : 0.f;
                xs[srow][f] = y;
                lad_acc += lad;
            }
        }
    }

    // ---- write outputs: z then logdet
    for (int t = ln; t < 16 * FDIM; t += 64) {
        int s = t / FDIM, i = t % FDIM;
        out[(size_t)(sbase + s) * FDIM + i] = xs[s][i];
    }
    float v = lad_acc;
    v += __shfl_xor(v, 1, 4);
    v += __shfl_xor(v, 2, 4);
    if ((ln & 3) == 0)
        out[(size_t)BATCH * FDIM + sbase + srow] = v;
}

extern "C" void kernel_launch(void* const* d_in, const int* in_sizes, int n_in,
                              void* d_out, int out_size, void* d_ws, size_t ws_size,
                              hipStream_t stream) {
    const float* x  = (const float*)d_in[0];
    const float* Wi = (const float*)d_in[1];
    const float* bI = (const float*)d_in[2];
    const float* Wr = (const float*)d_in[3];
    const float* bR = (const float*)d_in[4];
    const float* Wo = (const float*)d_in[5];
    const float* bO = (const float*)d_in[6];
    bf16_t* wfrag = (bf16_t*)d_ws;

    preproc_kernel<<<(WFRAG_TOTAL + 255) / 256, 256, 0, stream>>>(Wi, Wr, Wo, wfrag);

    flow_kernel<<<BATCH / 64, 256, 0, stream>>>(x, wfrag, bI, bR, bO, (float*)d_out);
}

// Round 4
// 917.474 us; speedup vs baseline: 8.0645x; 1.8032x over previous
//
#include <hip/hip_runtime.h>
#include <hip/hip_bf16.h>

#define FDIM 15
#define HDIM 128
#define LNUM 12
#define NBINS 16
#define MDIM 47
#define FM 705
#define BATCH 65536
#define TAILF 3.0f
#define MIN_Wc 0.001f
#define MIN_Hc 0.001f
#define MIN_Dc 0.001f

typedef __bf16 bf16_t;
typedef __attribute__((ext_vector_type(8))) __bf16 bf16x8;
typedef __attribute__((ext_vector_type(4))) float f32x4;

// fragment counts per layer: init 8, residual 4*32=128, out 45*4=180 -> 316
#define FRAGS_PER_LAYER 316
#define FRAG_ELEMS 512          // 64 lanes * 8 bf16
#define WFRAG_TOTAL (LNUM * FRAGS_PER_LAYER * FRAG_ELEMS)

__device__ __forceinline__ float sp_softplus(float u) {
    return (u > 20.f) ? u : log1pf(expf(u));
}

// ---------------- preproc: build bf16 B-fragment-swizzled masked weights ----------------
__global__ void preproc_kernel(const float* __restrict__ Wi,
                               const float* __restrict__ Wr,
                               const float* __restrict__ Wo,
                               bf16_t* __restrict__ wfrag) {
    int idx = blockIdx.x * blockDim.x + threadIdx.x;
    if (idx >= WFRAG_TOTAL) return;
    int j = idx & 7;
    int lane = (idx >> 3) & 63;
    int fg = idx >> 9;
    int g = fg % FRAGS_PER_LAYER;
    int l = fg / FRAGS_PER_LAYER;
    int quad = lane >> 4, n16 = lane & 15;
    int kk = quad * 8 + j;
    float val = 0.f;
    if (g < 8) {
        int n = g * 16 + n16;
        if (kk < FDIM && (n % 14) >= kk)
            val = Wi[(l * HDIM + n) * FDIM + kk];
    } else if (g < 136) {
        int gg = g - 8;
        int mat = gg >> 5, rem = gg & 31, nt = rem >> 2, s = rem & 3;
        int k = s * 32 + kk;
        int jc = nt * 16 + n16;
        if ((jc % 14) >= (k % 14))
            val = Wr[((size_t)(l * 4 + mat) * HDIM + jc) * HDIM + k];
    } else {
        int gg = g - 136;
        int tt = gg >> 2, s = gg & 3;
        int k = s * 32 + kk;
        int f = tt / 3, ty = tt % 3;
        int o = (ty < 2) ? (f * MDIM + ty * 16 + n16)
                         : ((n16 < 15) ? (f * MDIM + 32 + n16) : -1);
        if (o >= 0 && (f + 1) > (k % 14 + 1))
            val = Wo[((size_t)l * FM + o) * HDIM + k];
    }
    wfrag[idx] = (bf16_t)val;
}

// ---------------- helpers ----------------
__device__ __forceinline__ void stage16x128(bf16_t (*A)[136], const f32x4* frags,
                                            int quad, int n16, bool relu) {
#pragma unroll
    for (int nt = 0; nt < 8; nt++) {
#pragma unroll
        for (int reg = 0; reg < 4; reg++) {
            float v = frags[nt][reg];
            if (relu) v = fmaxf(v, 0.f);
            A[quad * 4 + reg][nt * 16 + n16] = (bf16_t)v;
        }
    }
}

__device__ __forceinline__ void loadA(bf16x8* af, const bf16_t (*A)[136], int quad, int n16) {
#pragma unroll
    for (int s = 0; s < 4; s++)
        af[s] = *(const bf16x8*)&A[n16][s * 32 + quad * 8];
}

// 128x128 GEMM, software-pipelined B loads (4 in flight ahead)
__device__ __forceinline__ void mm128(f32x4* dst, const bf16x8* af,
                                      const bf16_t* __restrict__ wb,
                                      const float* __restrict__ bias,
                                      int n16, int ln) {
    bf16x8 cur[4], nxt[4];
#pragma unroll
    for (int s = 0; s < 4; s++) cur[s] = *(const bf16x8*)(wb + (s << 9) + ln * 8);
#pragma unroll
    for (int nt = 0; nt < 8; nt++) {
        if (nt < 7) {
#pragma unroll
            for (int s = 0; s < 4; s++)
                nxt[s] = *(const bf16x8*)(wb + (((nt + 1) * 4 + s) << 9) + ln * 8);
        }
        float bv = bias[nt * 16 + n16];
        f32x4 acc = {bv, bv, bv, bv};
#pragma unroll
        for (int s = 0; s < 4; s++)
            acc = __builtin_amdgcn_mfma_f32_16x16x32_bf16(af[s], cur[s], acc, 0, 0, 0);
        dst[nt] = acc;
#pragma unroll
        for (int s = 0; s < 4; s++) cur[s] = nxt[s];
    }
}

// ---------------- per-layer kernel: one wave = 16 samples ----------------
__global__ __launch_bounds__(256, 2) void layer_kernel(
    const float* __restrict__ xin,
    float* __restrict__ xout,
    const float* __restrict__ ldin,
    float* __restrict__ ldout,
    const bf16_t* __restrict__ wl,
    const float* __restrict__ bI,
    const float* __restrict__ bR,
    const float* __restrict__ bO,
    int first) {

    __shared__ __align__(16) bf16_t Ast[4][16][136];
    __shared__ float raws[4][16][4][49];
    __shared__ float xss[4][16][17];

    const int wv = threadIdx.x >> 6, ln = threadIdx.x & 63;
    const int quad = ln >> 4, n16 = ln & 15;
    const int fi = ln & 3, srow = ln >> 2;
    const int sbase = (blockIdx.x * 4 + wv) * 16;

    bf16_t (*A)[136] = Ast[wv];
    float (*raw)[4][49] = raws[wv];
    float (*xs)[17] = xss[wv];

    // load x (16 samples x 15), unreversed
    for (int t = ln; t < 16 * FDIM; t += 64) {
        int s = t / FDIM, i = t % FDIM;
        xs[s][i] = xin[(size_t)(sbase + s) * FDIM + i];
    }

    // preload spline x-inputs (reversed frame) before xs gets overwritten
    float xc_pre[4];
#pragma unroll
    for (int c = 0; c < 4; c++) {
        int f = c * 4 + fi;
        xc_pre[c] = xs[srow][(f < FDIM) ? (14 - f) : 0];
    }

    // ---- init GEMM: A built in-register from reversed xs, K=32 (padded)
    bf16x8 a0;
#pragma unroll
    for (int j = 0; j < 8; j++) {
        int k = quad * 8 + j;
        float v = (k < FDIM) ? xs[n16][14 - k] : 0.f;
        a0[j] = (bf16_t)v;
    }
    f32x4 h[8];
    {
        bf16x8 bi8[8];
#pragma unroll
        for (int nt = 0; nt < 8; nt++)
            bi8[nt] = *(const bf16x8*)(wl + ((size_t)nt << 9) + ln * 8);
#pragma unroll
        for (int nt = 0; nt < 8; nt++) {
            float bv = bI[nt * 16 + n16];
            f32x4 acc = {bv, bv, bv, bv};
            h[nt] = __builtin_amdgcn_mfma_f32_16x16x32_bf16(a0, bi8[nt], acc, 0, 0, 0);
        }
    }

    // ---- two residual blocks
    bf16x8 af[4];
#pragma unroll
    for (int blk = 0; blk < 2; blk++) {
        f32x4 t[8];
        stage16x128(A, h, quad, n16, true);
        loadA(af, A, quad, n16);
        mm128(t, af, wl + (size_t)(8 + (blk * 2 + 0) * 32) * FRAG_ELEMS,
              bR + (size_t)(blk * 2 + 0) * HDIM, n16, ln);
        stage16x128(A, t, quad, n16, true);
        loadA(af, A, quad, n16);
        mm128(t, af, wl + (size_t)(8 + (blk * 2 + 1) * 32) * FRAG_ELEMS,
              bR + (size_t)(blk * 2 + 1) * HDIM, n16, ln);
#pragma unroll
        for (int nt = 0; nt < 8; nt++) h[nt] += t[nt];
    }

    // ---- out GEMM staged A = h (no relu), reused across all chunks
    stage16x128(A, h, quad, n16, false);
    loadA(af, A, quad, n16);
    const bf16_t* wo = wl + (size_t)136 * FRAG_ELEMS;

    float lad_acc = 0.f;

#pragma unroll
    for (int c = 0; c < 4; c++) {
        const int nf = (c < 3) ? 4 : 3;
        const int ng = nf * 3;
        bf16x8 cur[4], nxt[4];
#pragma unroll
        for (int s = 0; s < 4; s++)
            cur[s] = *(const bf16x8*)(wo + (((size_t)(c * 12) * 4 + s) << 9) + ln * 8);

        for (int g = 0; g < ng; g++) {
            if (g + 1 < ng) {
#pragma unroll
                for (int s = 0; s < 4; s++)
                    nxt[s] = *(const bf16x8*)(wo + (((size_t)(c * 12 + g + 1) * 4 + s) << 9) + ln * 8);
            }
            int ff = g / 3, ty = g % 3;
            int f = c * 4 + ff;
            int o = (ty < 2) ? (f * MDIM + ty * 16 + n16)
                             : ((n16 < 15) ? (f * MDIM + 32 + n16) : -1);
            float bv = (o >= 0) ? bO[o] : 0.f;
            f32x4 acc = {bv, bv, bv, bv};
#pragma unroll
            for (int s = 0; s < 4; s++)
                acc = __builtin_amdgcn_mfma_f32_16x16x32_bf16(af[s], cur[s], acc, 0, 0, 0);
#pragma unroll
            for (int reg = 0; reg < 4; reg++)
                raw[quad * 4 + reg][ff][ty * 16 + n16] = acc[reg];
#pragma unroll
            for (int s = 0; s < 4; s++) cur[s] = nxt[s];
        }

        // ---- spline: one per lane (sample srow, feature c*4+fi)
        if (fi < nf) {
            int f = c * 4 + fi;
            const float* rp = raw[srow][fi];
            float xr = xc_pre[c];
            bool inside = (xr >= -TAILF) && (xr <= TAILF);
            float xcv = fminf(fmaxf(xr, -TAILF), TAILF);

            float uw[NBINS], uh[NBINS];
            float mw = -1e30f, mh = -1e30f;
#pragma unroll
            for (int i = 0; i < NBINS; i++) {
                uw[i] = rp[i]; uh[i] = rp[NBINS + i];
                mw = fmaxf(mw, uw[i]); mh = fmaxf(mh, uh[i]);
            }
            float swv = 0.f, shv = 0.f;
#pragma unroll
            for (int i = 0; i < NBINS; i++) {
                uw[i] = expf(uw[i] - mw); swv += uw[i];
                uh[i] = expf(uh[i] - mh); shv += uh[i];
            }
            float isw = (1.f - NBINS * MIN_Wc) / swv;
            float ish = (1.f - NBINS * MIN_Hc) / shv;

            float cumw = 0.f, cumh = 0.f;
            float left = -TAILF, chl_run = -TAILF;
            float lw = -TAILF, wsel = 1.f, chl = -TAILF, hsel = 1.f;
            int idx = 0;
#pragma unroll
            for (int b = 0; b < NBINS; b++) {
                float wb = MIN_Wc + uw[b] * isw;
                float hb = MIN_Hc + uh[b] * ish;
                cumw += wb; cumh += hb;
                float cwr = (b == NBINS - 1) ? TAILF : 2.f * TAILF * cumw - TAILF;
                float chr = (b == NBINS - 1) ? TAILF : 2.f * TAILF * cumh - TAILF;
                bool inb = (xcv >= left) && ((xcv < cwr) || (b == NBINS - 1));
                if (inb) { idx = b; lw = left; wsel = cwr - left; chl = chl_run; hsel = chr - chl_run; }
                left = cwr; chl_run = chr;
            }
            float d0 = 1.f, d1 = 1.f;
            if (idx > 0) d0 = MIN_Dc + sp_softplus(rp[2 * NBINS + idx - 1]);
            if (idx < NBINS - 1) d1 = MIN_Dc + sp_softplus(rp[2 * NBINS + idx]);

            float delta = hsel / wsel;
            float th = (xcv - lw) / wsel;
            float omt = 1.f - th;
            float tomt = th * omt;
            float num = hsel * (delta * th * th + d0 * tomt);
            float den = delta + (d0 + d1 - 2.f * delta) * tomt;
            float y = chl + num / den;
            float dnum = delta * delta * (d1 * th * th + 2.f * delta * tomt + d0 * omt * omt);
            float lad = logf(dnum) - 2.f * logf(den);

            y = inside ? y : xr;
            lad = inside ? lad : 0.f;
            xs[srow][f] = y;
            lad_acc += lad;
        }
    }

    // ---- write x carry
    for (int t = ln; t < 16 * FDIM; t += 64) {
        int s = t / FDIM, i = t % FDIM;
        xout[(size_t)(sbase + s) * FDIM + i] = xs[s][i];
    }
    // ---- logdet accumulate
    float v = lad_acc;
    v += __shfl_xor(v, 1, 4);
    v += __shfl_xor(v, 2, 4);
    if ((ln & 3) == 0) {
        size_t gs = (size_t)sbase + srow;
        float prev = first ? 0.f : ldin[gs];
        ldout[gs] = prev + v;
    }
}

extern "C" void kernel_launch(void* const* d_in, const int* in_sizes, int n_in,
                              void* d_out, int out_size, void* d_ws, size_t ws_size,
                              hipStream_t stream) {
    const float* x  = (const float*)d_in[0];
    const float* Wi = (const float*)d_in[1];
    const float* bI = (const float*)d_in[2];
    const float* Wr = (const float*)d_in[3];
    const float* bR = (const float*)d_in[4];
    const float* Wo = (const float*)d_in[5];
    const float* bO = (const float*)d_in[6];

    bf16_t* wfrag = (bf16_t*)d_ws;
    size_t woff = ((size_t)WFRAG_TOTAL * 2 + 255) & ~(size_t)255;
    float* xbuf  = (float*)((char*)d_ws + woff);
    float* ldbuf = xbuf + (size_t)BATCH * FDIM;
    float* zout  = (float*)d_out;
    float* ldout_final = zout + (size_t)BATCH * FDIM;

    preproc_kernel<<<(WFRAG_TOTAL + 255) / 256, 256, 0, stream>>>(Wi, Wr, Wo, wfrag);

    for (int l = 0; l < LNUM; l++) {
        const float* xi = (l == 0) ? x : xbuf;
        float* xo = (l == LNUM - 1) ? zout : xbuf;
        float* ldo = (l == LNUM - 1) ? ldout_final : ldbuf;
        layer_kernel<<<BATCH / 64, 256, 0, stream>>>(
            xi, xo, ldbuf, ldo,
            wfrag + (size_t)l * FRAGS_PER_LAYER * FRAG_ELEMS,
            bI + (size_t)l * HDIM,
            bR + (size_t)l * 4 * HDIM,
            bO + (size_t)l * FM,
            (l == 0) ? 1 : 0);
    }
}